// Round 3
// baseline (176.082 us; speedup 1.0000x reference)
//
#include <hip/hip_runtime.h>
#include <stdint.h>

#define B_ 32
#define E_ 256
#define L_ 2048
#define D_ 256

#define BE 64
#define BD 128
#define BK 32
#define KS 4                  // k-split factor
#define KCHUNK (L_ / KS)      // 512
#define NKT (KCHUNK / BK)     // 16 k-tiles per block

typedef __attribute__((ext_vector_type(4))) float  f32x4;
typedef __attribute__((ext_vector_type(4))) short  s16x4;
typedef __attribute__((ext_vector_type(8))) short  s16x8;

// fp32 -> (hi, lo) bf16 pair. hi = truncated bf16(x); lo = bf16(x - hi).
__device__ __forceinline__ void cvt_hilo1(float x, short &h, short &l) {
    unsigned u = __builtin_bit_cast(unsigned, x);
    h = (short)(u >> 16);
    float hf = __builtin_bit_cast(float, u & 0xFFFF0000u);
    unsigned r = __builtin_bit_cast(unsigned, x - hf);
    l = (short)(r >> 16);
}

__global__ void zero_out_kernel(f32x4* __restrict__ out) {
    out[(size_t)blockIdx.x * 256 + threadIdx.x] = f32x4{0.f, 0.f, 0.f, 0.f};
}

__global__ __launch_bounds__(512, 8)
void mean_pool_kernel(const float* __restrict__ doc,
                      const float* __restrict__ emap,
                      const float* __restrict__ lens,
                      float* __restrict__ out) {
    // LDS 24,832 B -> 4 blocks/CU (wave-limit saturated: 32/32 waves).
    // A swizzle key: row&3.  B swizzle key: (row>>1)&3.  Both make every
    // LDS read & write hit all 32 banks at the minimum cycle count.
    __shared__ __align__(16) short As_hi[BE][BK];
    __shared__ __align__(16) short As_lo[BE][BK];
    __shared__ __align__(16) short Bs_hi[BD][BK];   // doc^T tile: [d][k]
    __shared__ __align__(16) short Bs_lo[BD][BK];
    __shared__ float lens_s[BE];

    const int t   = threadIdx.x;
    const int blk = blockIdx.x;
    const int ks  = blk & 3;
    const int d0  = ((blk >> 2) & 1) * BD;
    const int e0  = ((blk >> 3) & 3) * BE;
    const int b   = blk >> 5;

    const float* Ag = emap + ((size_t)b * E_ + e0) * L_ + ks * KCHUNK;
    const float* Sg = doc  + (size_t)b * L_ * D_ + (size_t)ks * KCHUNK * D_ + d0;

    if (t < BE) lens_s[t] = lens[b * E_ + e0 + t];

    // A staging: one 64-row x 32-k tile; thread t loads float4 at
    // row a_r = t>>3, k = (t&7)*4. One row per thread.
    const int a_c4 = t & 7;
    const int a_r  = t >> 3;
    // B staging: 8k x 1d per thread: d = t&127, k-group = t>>7 (0..3) -> k = g*8.
    const int b_d  = t & 127;
    const int b_g  = t >> 7;

    // wave coords: 8 waves as 2(e) x 4(d), wave tile 32e x 32d
    const int lane = t & 63;
    const int w    = t >> 6;
    const int eo   = (w & 1) * 32;
    const int dq   = (w >> 1) * 32;
    const int ml   = lane & 15;
    const int kg   = lane >> 4;   // 0..3

    f32x4 acc[2][2] = {};
    f32x4 pa;
    float pb[8];

    // preload tile 0
    pa = *(const f32x4*)(Ag + (size_t)a_r * L_ + a_c4 * 4);
    #pragma unroll
    for (int j = 0; j < 8; ++j)
        pb[j] = Sg[(size_t)(b_g * 8 + j) * D_ + b_d];

    for (int kt = 0; kt < NKT; ++kt) {
        // ---- convert & stage to LDS ----
        {
            s16x4 h, l;
            #pragma unroll
            for (int i = 0; i < 4; ++i) { short hh, ll; cvt_hilo1(pa[i], hh, ll); h[i] = hh; l[i] = ll; }
            const int col = (((a_c4 >> 1) ^ (a_r & 3)) << 3) + (a_c4 & 1) * 4;
            *(s16x4*)&As_hi[a_r][col] = h;
            *(s16x4*)&As_lo[a_r][col] = l;
        }
        {
            s16x8 h, l;
            #pragma unroll
            for (int j = 0; j < 8; ++j) {
                short hh, ll; cvt_hilo1(pb[j], hh, ll);
                h[j] = hh; l[j] = ll;
            }
            const int col = (b_g ^ ((b_d >> 1) & 3)) << 3;
            *(s16x8*)&Bs_hi[b_d][col] = h;
            *(s16x8*)&Bs_lo[b_d][col] = l;
        }
        __syncthreads();

        // ---- prefetch next tile's globals (completes during MFMA phase) ----
        if (kt + 1 < NKT) {
            const int k0 = (kt + 1) * BK;
            pa = *(const f32x4*)(Ag + (size_t)a_r * L_ + k0 + a_c4 * 4);
            #pragma unroll
            for (int j = 0; j < 8; ++j)
                pb[j] = Sg[(size_t)(k0 + b_g * 8 + j) * D_ + b_d];
        }

        // ---- MFMA: single k-pass (BK=32), 3-pass hi/lo split ----
        {
            s16x8 ah[2], al[2], bh[2], bl[2];
            #pragma unroll
            for (int mi = 0; mi < 2; ++mi) {
                const int row = eo + mi * 16 + ml;
                const int col = (kg ^ (row & 3)) << 3;
                ah[mi] = *(const s16x8*)&As_hi[row][col];
                al[mi] = *(const s16x8*)&As_lo[row][col];
            }
            #pragma unroll
            for (int ni = 0; ni < 2; ++ni) {
                const int row = dq + ni * 16 + ml;
                const int col = (kg ^ ((row >> 1) & 3)) << 3;
                bh[ni] = *(const s16x8*)&Bs_hi[row][col];
                bl[ni] = *(const s16x8*)&Bs_lo[row][col];
            }
            #pragma unroll
            for (int mi = 0; mi < 2; ++mi)
                #pragma unroll
                for (int ni = 0; ni < 2; ++ni) {
                    acc[mi][ni] = __builtin_amdgcn_mfma_f32_16x16x32_bf16(ah[mi], bh[ni], acc[mi][ni], 0, 0, 0);
                    acc[mi][ni] = __builtin_amdgcn_mfma_f32_16x16x32_bf16(ah[mi], bl[ni], acc[mi][ni], 0, 0, 0);
                    acc[mi][ni] = __builtin_amdgcn_mfma_f32_16x16x32_bf16(al[mi], bh[ni], acc[mi][ni], 0, 0, 0);
                }
        }
        __syncthreads();
    }

    // ---- epilogue: divide by entity_lens, atomically accumulate k-split partials ----
    #pragma unroll
    for (int mi = 0; mi < 2; ++mi) {
        #pragma unroll
        for (int rr = 0; rr < 4; ++rr) {
            const int er = eo + mi * 16 + kg * 4 + rr;
            const float lv = lens_s[er];
            #pragma unroll
            for (int ni = 0; ni < 2; ++ni) {
                atomicAdd(&out[((size_t)(b * E_ + e0 + er)) * D_ + d0 + dq + ni * 16 + ml],
                          acc[mi][ni][rr] / lv);
            }
        }
    }
}

extern "C" void kernel_launch(void* const* d_in, const int* in_sizes, int n_in,
                              void* d_out, int out_size, void* d_ws, size_t ws_size,
                              hipStream_t stream) {
    const float* doc  = (const float*)d_in[0];   // [32][2048][256]
    const float* emap = (const float*)d_in[1];   // [32][256][2048]
    const float* lens = (const float*)d_in[2];   // [32][256]
    float* out = (float*)d_out;                  // [32][256][256]

    // zero the output (harness poisons it with 0xAA), then accumulate partials
    zero_out_kernel<<<dim3(out_size / (4 * 256)), dim3(256), 0, stream>>>((f32x4*)out);

    dim3 grid(B_ * (E_ / BE) * (D_ / BD) * KS);  // 1024 workgroups = 4/CU
    dim3 block(512);
    hipLaunchKernelGGL(mean_pool_kernel, grid, block, 0, stream,
                       doc, emap, lens, out);
}